// Round 14
// baseline (68.639 us; speedup 1.0000x reference)
//
#include <hip/hip_runtime.h>
#include <hip/hip_bf16.h>
#include <math.h>

#define EPS   1e-5f
#define EPS2  (1e-5f * 1e-5f)
#define MAXN  (1.0f - 1e-4f)

typedef __attribute__((ext_vector_type(8))) short bf16x8;
typedef __attribute__((ext_vector_type(4))) float f32x4;

__device__ __forceinline__ float artanh_(float x) {   // fast: 0.5*log((1+x)/(1-x))
    x = fminf(fmaxf(x, -1.0f + 1e-5f), 1.0f - 1e-5f);
    return 0.5f * __logf((1.0f + x) / (1.0f - x));
}
__device__ __forceinline__ float tanh_pos(float x) {  // x >= 0
    float t = __expf(-2.0f * x);
    return (1.0f - t) / (1.0f + t);
}
__device__ __forceinline__ float redw(float v) {   // sum over 64 lanes
    #pragma unroll
    for (int m = 32; m >= 1; m >>= 1) v += __shfl_xor(v, m);
    return v;
}
__device__ __forceinline__ float red16(float v) {  // sum over 16-lane group
    v += __shfl_xor(v, 1); v += __shfl_xor(v, 2);
    v += __shfl_xor(v, 4); v += __shfl_xor(v, 8);
    return v;
}
__device__ __forceinline__ float red8(float v) {   // sum over 8-lane group
    v += __shfl_xor(v, 1); v += __shfl_xor(v, 2); v += __shfl_xor(v, 4);
    return v;
}
__device__ __forceinline__ float sigmoid_(float z) { return 1.0f / (1.0f + __expf(-z)); }
__device__ __forceinline__ ushort f2bf(float f) {
    union { __hip_bfloat16 b; ushort u; } cv;
    cv.b = __float2bfloat16(f);
    return cv.u;
}

// ---------------------------------------------------------------------------
// K1: blocks 0..1023: token pipeline (x written bf16); blocks 1024..1040:
//     convert expW -> bf16.
// ---------------------------------------------------------------------------
__global__ __launch_bounds__(256) void k1_token(
    const int* __restrict__ tokens, const float* __restrict__ emb,
    const float* __restrict__ conv_w, const float* __restrict__ conv_b,
    const float* __restrict__ lin_w, const float* __restrict__ lin_b,
    ushort* __restrict__ x_out, float* __restrict__ xn_out,
    float* __restrict__ p_out, float* __restrict__ logp_out,
    const float* __restrict__ expW, ushort* __restrict__ expWb)
{
    if (blockIdx.x >= 1024) {            // W conversion blocks
        const int k = blockIdx.x - 1024;
        const float* src = expW + k * 4096 + threadIdx.x * 16;
        ushort* dst = expWb + k * 4096 + threadIdx.x * 16;
        #pragma unroll
        for (int i = 0; i < 4; ++i) {
            float4 v = *reinterpret_cast<const float4*>(src + i * 4);
            ushort4 o;
            o.x = f2bf(v.x); o.y = f2bf(v.y); o.z = f2bf(v.z); o.w = f2bf(v.w);
            *reinterpret_cast<ushort4*>(dst + i * 4) = o;
        }
        return;
    }

    const int tok = blockIdx.x * 4 + (threadIdx.x >> 6);   // 0..4095
    const int t   = tok & 511;
    const int c   = threadIdx.x & 63;

    const int id0 = tokens[tok];
    float h0 = emb[id0 * 64 + c];
    float hm = 0.0f, hp = 0.0f;
    if (t > 0)   hm = emb[tokens[tok - 1] * 64 + c];
    if (t < 511) hp = emb[tokens[tok + 1] * 64 + c];

    float hc = conv_w[c * 3 + 0] * hm + conv_w[c * 3 + 1] * h0 +
               conv_w[c * 3 + 2] * hp + conv_b[c];

    // router matvec: lane j keeps logit j
    float myLg = 0.0f;
    #pragma unroll
    for (int j = 0; j < 17; ++j) {
        float v = redw(hc * lin_w[c * 17 + j]);
        if (c == j) myLg = v + lin_b[j];
    }
    // log_softmax over lanes 0..16 (register)
    float mx = (c < 17) ? myLg : -1e30f;
    #pragma unroll
    for (int m = 32; m >= 1; m >>= 1) mx = fmaxf(mx, __shfl_xor(mx, m));
    float ev = (c < 17) ? __expf(myLg - mx) : 0.0f;
    float se = redw(ev);
    float lse = __logf(se);
    if (c < 17) {
        float lp = myLg - mx - lse;
        logp_out[tok * 17 + c] = lp;
        p_out[tok * 17 + c]    = __expf(lp);
    }

    // project(h0)
    float n0 = sqrtf(fmaxf(redw(h0 * h0), EPS2));
    float xp = h0 * fminf(1.0f, MAXN / n0);
    // logmap0
    float n1 = sqrtf(fmaxf(redw(xp * xp), EPS2));
    float v1 = artanh_(n1) / n1 * xp;
    // expmap0
    float n2 = sqrtf(fmaxf(redw(v1 * v1), EPS2));
    float xv = tanh_pos(n2) / n2 * v1;

    x_out[tok * 64 + c] = f2bf(xv);
    float n3 = sqrtf(fmaxf(redw(xv * xv), EPS2));
    if (c == 0) xn_out[tok] = n3;
}

// ---------------------------------------------------------------------------
// K2: one (16-token chunk, expert k) per block — 4352 blocks.
// MFMA matvec (bf16 operands preconverted); register projected-bias;
// hyperbolic chain; bf16 partial to yk[tok][k][32].
// ---------------------------------------------------------------------------
__global__ __launch_bounds__(256) void k2_expert(
    const ushort* __restrict__ xb, const float* __restrict__ xn_in,
    const float* __restrict__ p_in, const ushort* __restrict__ Wb,
    const float* __restrict__ expB, const float* __restrict__ g_in,
    const float* __restrict__ b_in, __hip_bfloat16* __restrict__ yk_out)
{
    __shared__ float mv_s[16][65];   // mv transpose bounce (2-way banks = free)

    const int tid = threadIdx.x;
    const int l = tid & 63, w = tid >> 6;
    const int tg = tid >> 4, eg = tid & 15;
    const int k = blockIdx.x >> 8;          // 0..16
    const int chunk = blockIdx.x & 255;     // 0..255
    const int tok0 = chunk * 16;

    // ---- MFMA matvec: mv[tok][e] = sum_d x[tok][d] * W[k][e][d]
    {
        const int d0 = (l >> 4) * 8;
        const ushort* ap = xb + (tok0 + (l & 15)) * 64 + d0;
        const ushort* bp = Wb + k * 4096 + (16 * w + (l & 15)) * 64 + d0;
        bf16x8 a0 = *reinterpret_cast<const bf16x8*>(ap);
        bf16x8 a1 = *reinterpret_cast<const bf16x8*>(ap + 32);
        bf16x8 b0 = *reinterpret_cast<const bf16x8*>(bp);
        bf16x8 b1 = *reinterpret_cast<const bf16x8*>(bp + 32);
        f32x4 acc = {0.f, 0.f, 0.f, 0.f};
        acc = __builtin_amdgcn_mfma_f32_16x16x32_bf16(a0, b0, acc, 0, 0, 0);
        acc = __builtin_amdgcn_mfma_f32_16x16x32_bf16(a1, b1, acc, 0, 0, 0);
        #pragma unroll
        for (int q = 0; q < 4; ++q)
            mv_s[(l >> 4) * 4 + q][16 * w + (l & 15)] = acc[q];
    }

    // ---- projected bias: per-wave, register-only
    float wv = expB[k * 64 + l];
    float s  = redw(wv * wv);
    float nB = sqrtf(fmaxf(s, EPS2));
    float scB = fminf(1.0f, MAXN / nB);
    float y2 = s * scB * scB;
    float pb0 = __shfl(wv, eg * 4 + 0) * scB;
    float pb1 = __shfl(wv, eg * 4 + 1) * scB;
    float pb2 = __shfl(wv, eg * 4 + 2) * scB;
    float pb3 = __shfl(wv, eg * 4 + 3) * scB;

    // ---- small params: direct per-thread loads
    const int c0 = 4 * (eg & 7);
    float4 gq = *reinterpret_cast<const float4*>(g_in + k * 32 + c0);
    float4 bq = *reinterpret_cast<const float4*>(b_in + k * 32 + c0);
    float pk  = p_in[(tok0 + tg) * 17 + k];
    float xnv = xn_in[tok0 + tg];
    float axnv = artanh_(xnv);

    __syncthreads();

    float4 mvq = *reinterpret_cast<const float4*>(&mv_s[tg][eg * 4]);
    float mv0 = mvq.x, mv1 = mvq.y, mv2 = mvq.z, mv3 = mvq.w;

    // mobius matvec scaling
    float mn = sqrtf(fmaxf(red16(mv0*mv0 + mv1*mv1 + mv2*mv2 + mv3*mv3), EPS2));
    float tv = tanh_pos(mn / xnv * axnv);
    float cf = tv / mn;
    float xa0 = cf * mv0, xa1 = cf * mv1, xa2 = cf * mv2, xa3 = cf * mv3;
    float x2 = tv * tv;

    // mobius_add(xa, pb)
    float xy = red16(xa0*pb0 + xa1*pb1 + xa2*pb2 + xa3*pb3);
    float ca = 1.0f + 2.0f * xy + y2;
    float cb = 1.0f - x2;
    float den = fmaxf(1.0f + 2.0f * xy + x2 * y2, EPS);
    float rden = 1.0f / den;
    float y0 = (ca * xa0 + cb * pb0) * rden;
    float y1 = (ca * xa1 + cb * pb1) * rden;
    float y2c = (ca * xa2 + cb * pb2) * rden;
    float y3 = (ca * xa3 + cb * pb3) * rden;

    // project
    float s2 = red16(y0*y0 + y1*y1 + y2c*y2c + y3*y3);
    float nP = sqrtf(fmaxf(s2, EPS2));
    float scP = fminf(1.0f, MAXN / nP);
    y0 *= scP; y1 *= scP; y2c *= scP; y3 *= scP;

    // logmap0
    float n2 = sqrtf(fmaxf(s2 * scP * scP, EPS2));
    float lc = artanh_(n2) / n2;
    float yt0 = lc * y0, yt1 = lc * y1, yt2 = lc * y2c, yt3 = lc * y3;

    // GLU via lane-pair exchange (eg<8 hold a, eg>=8 hold g); halves duplicate
    float pr0 = __shfl_xor(yt0, 8), pr1 = __shfl_xor(yt1, 8);
    float pr2 = __shfl_xor(yt2, 8), pr3 = __shfl_xor(yt3, 8);
    float gl0, gl1, gl2, gl3;
    if (eg < 8) {
        gl0 = yt0 * sigmoid_(pr0); gl1 = yt1 * sigmoid_(pr1);
        gl2 = yt2 * sigmoid_(pr2); gl3 = yt3 * sigmoid_(pr3);
    } else {
        gl0 = pr0 * sigmoid_(yt0); gl1 = pr1 * sigmoid_(yt1);
        gl2 = pr2 * sigmoid_(yt2); gl3 = pr3 * sigmoid_(yt3);
    }

    // LayerNorm over 32 (each 8-lane half holds full set)
    float mu = red8(gl0 + gl1 + gl2 + gl3) * (1.0f / 32.0f);
    float sq = red8(gl0*gl0 + gl1*gl1 + gl2*gl2 + gl3*gl3) * (1.0f / 32.0f);
    float rstd = rsqrtf(fmaxf(sq - mu * mu, 0.0f) + 1e-5f);
    float ln0 = (gl0 - mu) * rstd * gq.x + bq.x;
    float ln1 = (gl1 - mu) * rstd * gq.y + bq.y;
    float ln2 = (gl2 - mu) * rstd * gq.z + bq.z;
    float ln3 = (gl3 - mu) * rstd * gq.w + bq.w;

    // expmap0
    float n3 = sqrtf(fmaxf(red8(ln0*ln0 + ln1*ln1 + ln2*ln2 + ln3*ln3), EPS2));
    float tc = tanh_pos(n3) / n3;

    // p-weighted partial for this expert
    float wq = pk * tc;

    if (eg < 8) {
        int tok = tok0 + tg;
        ushort4 o;
        o.x = f2bf(wq * ln0);
        o.y = f2bf(wq * ln1);
        o.z = f2bf(wq * ln2);
        o.w = f2bf(wq * ln3);
        *reinterpret_cast<ushort4*>(
            reinterpret_cast<ushort*>(yk_out) + ((size_t)tok * 17 + k) * 32 + c0) = o;
    }
}

// ---------------------------------------------------------------------------
// K4: self-reduce ya rows from yk (k3 eliminated; safe: kernel boundary after
// k2 flushes), then per r in pair: M_r = T_r S_r^T, Z = ya.M_r via MFMA.
// block = (b, r-pair, t-quarter) = 640 blocks, 4 waves, ~40KB LDS.
// rp==0 blocks zero pmax; rem==0 blocks zero per-b completion counters.
// ---------------------------------------------------------------------------
__global__ __launch_bounds__(256) void k4_rel(
    const __hip_bfloat16* __restrict__ yk, const float* __restrict__ relT,
    const float* __restrict__ relS, ushort* __restrict__ Z,
    unsigned long long* __restrict__ pmax, unsigned int* __restrict__ cnt)
{
    const int blk = blockIdx.x;          // 0..639
    const int b = blk / 80;
    const int rem = blk % 80;
    const int rp = rem >> 2, tq = rem & 3;   // r = 2*rp, 2*rp+1
    __shared__ float Ts[32][33], Ss[32][33], Mm[32][33];
    __shared__ float Zb[128][33];
    __shared__ ushort yas[128][40];          // rows padded to 40 bf16 (80B)
    const int tid = threadIdx.x;
    const int l = tid & 63, w = tid >> 6;

    if (rp == 0 && tid < 128)
        pmax[(size_t)b * 512 + tq * 128 + tid] = 0ull;
    if (rem == 0 && tid == 128)
        cnt[b] = 0u;

    // self-reduce: yas[row][e] = sum_k yk[b*512 + tq*128 + row][k][e]
    for (int i = tid; i < 4096; i += 256) {
        int row = i >> 5, e = i & 31;
        const __hip_bfloat16* p =
            yk + ((size_t)(b * 512 + tq * 128 + row) * 17) * 32 + e;
        float s = 0.0f;
        #pragma unroll
        for (int k = 0; k < 17; ++k) s += __bfloat162float(p[k * 32]);
        yas[row][e] = f2bf(s);
    }

    for (int rr = 2 * rp; rr <= 2 * rp + 1; ++rr) {
        __syncthreads();   // yas ready (iter 0) / prior Zb+Ts consumers done

        // stage T_r, S_r
        {
            int d = tid >> 3, e0 = (tid & 7) * 4;
            float4 wT = *reinterpret_cast<const float4*>(&relT[rr * 1024 + tid * 4]);
            float4 wS = *reinterpret_cast<const float4*>(&relS[rr * 1024 + tid * 4]);
            Ts[d][e0 + 0] = wT.x; Ts[d][e0 + 1] = wT.y;
            Ts[d][e0 + 2] = wT.z; Ts[d][e0 + 3] = wT.w;
            Ss[d][e0 + 0] = wS.x; Ss[d][e0 + 1] = wS.y;
            Ss[d][e0 + 2] = wS.z; Ss[d][e0 + 3] = wS.w;
        }
        __syncthreads();

        // M[d][dp] = sum_e Ts[d][e] * Ss[dp][e]
        {
            int d = tid >> 3, dp0 = (tid & 7) * 4;
            float m0 = 0.f, m1 = 0.f, m2 = 0.f, m3 = 0.f;
            #pragma unroll
            for (int e = 0; e < 32; ++e) {
                float tvv = Ts[d][e];
                m0 = fmaf(tvv, Ss[dp0 + 0][e], m0);
                m1 = fmaf(tvv, Ss[dp0 + 1][e], m1);
                m2 = fmaf(tvv, Ss[dp0 + 2][e], m2);
                m3 = fmaf(tvv, Ss[dp0 + 3][e], m3);
            }
            Mm[d][dp0 + 0] = m0; Mm[d][dp0 + 1] = m1;
            Mm[d][dp0 + 2] = m2; Mm[d][dp0 + 3] = m3;
        }
        __syncthreads();

        // B-frags: B[k=d][col=dp] = M[d][dp]
        bf16x8 bm0, bm1;
        #pragma unroll
        for (int i = 0; i < 8; ++i) {
            int d = (l >> 4) * 8 + i;
            bm0[i] = (short)f2bf(Mm[d][(l & 15)]);
            bm1[i] = (short)f2bf(Mm[d][16 + (l & 15)]);
        }

        // A-frags from yas (LDS); wave w covers t-tiles w*2, w*2+1
        #pragma unroll
        for (int s = 0; s < 2; ++s) {
            int lrow = (w * 2 + s) * 16 + (l & 15);
            bf16x8 a = *reinterpret_cast<const bf16x8*>(&yas[lrow][(l >> 4) * 8]);
            f32x4 acc0 = {0.f, 0.f, 0.f, 0.f}, acc1 = {0.f, 0.f, 0.f, 0.f};
            acc0 = __builtin_amdgcn_mfma_f32_16x16x32_bf16(a, bm0, acc0, 0, 0, 0);
            acc1 = __builtin_amdgcn_mfma_f32_16x16x32_bf16(a, bm1, acc1, 0, 0, 0);
            #pragma unroll
            for (int q = 0; q < 4; ++q) {
                int lr = (w * 2 + s) * 16 + (l >> 4) * 4 + q;
                Zb[lr][(l & 15)]      = acc0[q];
                Zb[lr][16 + (l & 15)] = acc1[q];
            }
        }
        __syncthreads();

        // coalesced bf16 write of Z[b][rr][tq*128 .. +127][:]
        {
            int t2 = tid >> 1, half = tid & 1;
            union { ushort u[16]; uint4 q[2]; } pk;
            #pragma unroll
            for (int j = 0; j < 16; ++j) pk.u[j] = f2bf(Zb[t2][half * 16 + j]);
            size_t off = ((size_t)(b * 40 + rr) * 512 + tq * 128 + t2) * 32 + half * 16;
            *reinterpret_cast<uint4*>(Z + off)     = pk.q[0];
            *reinterpret_cast<uint4*>(Z + off + 8) = pk.q[1];
        }
    }
}

// ---------------------------------------------------------------------------
// K5: self-reduce ya rows (jt..jt+63) from yk into LDS, then
// score = max_r Z_r . ya^T via MFMA (R8 structure, full occupancy);
// fused column-argmax into pmax; last block per b writes tree (no fence —
// __syncthreads drains the block's pmax atomics before the cnt increment).
// ---------------------------------------------------------------------------
__global__ __launch_bounds__(1024) void k5_scores(
    const __hip_bfloat16* __restrict__ yk, const ushort* __restrict__ Z,
    float* __restrict__ score_out, unsigned long long* __restrict__ pmax,
    unsigned int* __restrict__ cnt, float* __restrict__ tree)
{
    __shared__ float L[4][64][64];               // 64 KB
    __shared__ unsigned long long pk_s[16][64];  // 8 KB
    __shared__ ushort ybb[64][40];               // 5 KB
    __shared__ unsigned int last_s;

    const int blk = blockIdx.x;
    const int b = blk >> 6, tile = blk & 63;
    const int it = (tile >> 3) * 64, jt = (tile & 7) * 64;
    const int tid = threadIdx.x;
    const int w = tid >> 6, lane = tid & 63;
    const int q = w >> 2, s = w & 3;        // r-chunk, i-subtile
    const int i0 = it + s * 16;
    const int arow = i0 + (lane & 15);
    const int koff = (lane >> 4) * 8;

    // self-reduce ya rows jt..jt+63
    for (int i = tid; i < 2048; i += 1024) {
        int row = i >> 5, e = i & 31;
        const __hip_bfloat16* p =
            yk + ((size_t)(b * 512 + jt + row) * 17) * 32 + e;
        float sv = 0.0f;
        #pragma unroll
        for (int k = 0; k < 17; ++k) sv += __bfloat162float(p[k * 32]);
        ybb[row][e] = f2bf(sv);
    }
    __syncthreads();

    // b-fragments: ya rows for the 4 j-subtiles (r-invariant), from LDS
    bf16x8 bb[4];
    #pragma unroll
    for (int c = 0; c < 4; ++c) {
        int lrow = c * 16 + (lane & 15);
        bb[c] = *reinterpret_cast<const bf16x8*>(&ybb[lrow][koff]);
    }

    f32x4 runmax[4];
    #pragma unroll
    for (int c = 0; c < 4; ++c)
        #pragma unroll
        for (int qq = 0; qq < 4; ++qq) runmax[c][qq] = -3.0e38f;

    const int r0 = q * 10;
    #pragma unroll 2
    for (int r = r0; r < r0 + 10; ++r) {
        bf16x8 a = *reinterpret_cast<const bf16x8*>(
            Z + ((size_t)(b * 40 + r) * 512 + arow) * 32 + koff);
        #pragma unroll
        for (int c = 0; c < 4; ++c) {
            f32x4 acc = {0.f, 0.f, 0.f, 0.f};
            acc = __builtin_amdgcn_mfma_f32_16x16x32_bf16(a, bb[c], acc, 0, 0, 0);
            #pragma unroll
            for (int qq = 0; qq < 4; ++qq) runmax[c][qq] = fmaxf(runmax[c][qq], acc[qq]);
        }
    }

    // deposit partial max into LDS quadrant q
    #pragma unroll
    for (int c = 0; c < 4; ++c) {
        #pragma unroll
        for (int qq = 0; qq < 4; ++qq) {
            int li = s * 16 + (lane >> 4) * 4 + qq;
            int lj = c * 16 + (lane & 15);
            L[q][li][lj] = runmax[c][qq];
        }
    }
    __syncthreads();

    // combine 4 r-chunks, scale, diag-mask, store; track column argmax
    {
        const int jl = tid & 63, ig = tid >> 6;
        const int gj = jt + jl;
        float bestv = -3.0e38f; int besti = it;
        #pragma unroll
        for (int p = 0; p < 4; ++p) {
            int i = ig + p * 16;
            float v = fmaxf(fmaxf(L[0][i][jl], L[1][i][jl]),
                            fmaxf(L[2][i][jl], L[3][i][jl])) * (1.0f / 32.0f);
            int gi = it + i;
            if (gi == gj) v = -1e9f;
            score_out[((size_t)b * 512 + gi) * 512 + gj] = v;
            if (v > bestv) { bestv = v; besti = gi; }
        }
        unsigned int ub = __float_as_uint(bestv);
        unsigned int ok = (ub >> 31) ? ~ub : (ub | 0x80000000u);
        pk_s[ig][jl] = ((unsigned long long)ok << 32) | (unsigned int)(511 - besti);
    }
    __syncthreads();
    if (tid < 64) {
        unsigned long long best = pk_s[0][tid];
        #pragma unroll
        for (int g = 1; g < 16; ++g) {
            unsigned long long v = pk_s[g][tid];
            if (v > best) best = v;
        }
        atomicMax(&pmax[(size_t)b * 512 + jt + tid], best);
    }

    // completion protocol: __syncthreads drains this block's atomics
    // (compiler emits s_waitcnt vmcnt(0) before s_barrier) -> cnt increment
    // is globally ordered after our pmax updates. No device fence needed.
    __syncthreads();
    if (tid == 0) last_s = atomicAdd(&cnt[b], 1u);
    __syncthreads();
    if (last_s == 63u && tid < 512) {
        unsigned long long key = atomicMax(&pmax[(size_t)b * 512 + tid], 0ull);
        tree[b * 512 + tid] = (float)(511 - (int)(key & 0x1ffull));
    }
}

// ---------------------------------------------------------------------------
extern "C" void kernel_launch(void* const* d_in, const int* in_sizes, int n_in,
                              void* d_out, int out_size, void* d_ws, size_t ws_size,
                              hipStream_t stream)
{
    const int*   tokens  = (const int*)  d_in[0];
    const float* emb     = (const float*)d_in[1];
    const float* conv_w  = (const float*)d_in[2];
    const float* conv_b  = (const float*)d_in[3];
    const float* lin_w   = (const float*)d_in[4];
    const float* lin_b   = (const float*)d_in[5];
    const float* expW    = (const float*)d_in[6];
    const float* expB    = (const float*)d_in[7];
    const float* ln_g    = (const float*)d_in[8];
    const float* ln_b    = (const float*)d_in[9];
    const float* relT    = (const float*)d_in[10];
    const float* relS    = (const float*)d_in[11];

    float* out = (float*)d_out;
    float* tree_out  = out;                    // [8*512]
    float* score_out = out + 4096;             // [8*512*512]
    float* logp_out  = out + 4096 + 2097152;   // [8*512*17]

    float* ws = (float*)d_ws;
    ushort* xb_ws  = (ushort*)ws;               // 262144 bf16 (131072 f32 slots)
    float*  xn_ws  = ws + 131072;               // 4096
    float*  p_ws   = ws + 135168;               // 69632
    ushort* Wb_ws  = (ushort*)(ws + 204800);    // 69632 bf16 (34816 slots)
    __hip_bfloat16* yk_ws = (__hip_bfloat16*)(ws + 239616);   // 2228224 bf16
    ushort* Z_ws   = (ushort*)(ws + 1353728);   // 5242880 bf16 (2621440 slots)
    unsigned long long* pmax_ws =
        (unsigned long long*)(ws + 3975168);    // 4096 u64 (8192 f32 slots)
    unsigned int* cnt_ws = (unsigned int*)(ws + 3983360);     // 8 u32

    k1_token<<<1041, 256, 0, stream>>>(tokens, emb, conv_w, conv_b, lin_w, lin_b,
                                       xb_ws, xn_ws, p_ws, logp_out, expW, Wb_ws);
    k2_expert<<<4352, 256, 0, stream>>>(xb_ws, xn_ws, p_ws, Wb_ws, expB, ln_g, ln_b, yk_ws);
    k4_rel<<<640, 256, 0, stream>>>(yk_ws, relT, relS, Z_ws, pmax_ws, cnt_ws);
    k5_scores<<<512, 1024, 0, stream>>>(yk_ws, Z_ws, score_out, pmax_ws, cnt_ws, tree_out);
}

// Round 15
// 62.523 us; speedup vs baseline: 1.0978x; 1.0978x over previous
//
#include <hip/hip_runtime.h>
#include <hip/hip_bf16.h>
#include <math.h>

#define EPS   1e-5f
#define EPS2  (1e-5f * 1e-5f)
#define MAXN  (1.0f - 1e-4f)

typedef __attribute__((ext_vector_type(8))) short bf16x8;
typedef __attribute__((ext_vector_type(4))) float f32x4;

__device__ __forceinline__ float artanh_(float x) {   // fast: 0.5*log((1+x)/(1-x))
    x = fminf(fmaxf(x, -1.0f + 1e-5f), 1.0f - 1e-5f);
    return 0.5f * __logf((1.0f + x) / (1.0f - x));
}
__device__ __forceinline__ float tanh_pos(float x) {  // x >= 0
    float t = __expf(-2.0f * x);
    return (1.0f - t) / (1.0f + t);
}
__device__ __forceinline__ float redw(float v) {   // sum over 64 lanes
    #pragma unroll
    for (int m = 32; m >= 1; m >>= 1) v += __shfl_xor(v, m);
    return v;
}
__device__ __forceinline__ float red16(float v) {  // sum over 16-lane group
    v += __shfl_xor(v, 1); v += __shfl_xor(v, 2);
    v += __shfl_xor(v, 4); v += __shfl_xor(v, 8);
    return v;
}
__device__ __forceinline__ float sigmoid_(float z) { return 1.0f / (1.0f + __expf(-z)); }
__device__ __forceinline__ ushort f2bf(float f) {
    union { __hip_bfloat16 b; ushort u; } cv;
    cv.b = __float2bfloat16(f);
    return cv.u;
}

// ---------------------------------------------------------------------------
// K1: blocks 0..1023: token pipeline (x written bf16); blocks 1024..1040:
//     convert expW -> bf16.
// ---------------------------------------------------------------------------
__global__ __launch_bounds__(256) void k1_token(
    const int* __restrict__ tokens, const float* __restrict__ emb,
    const float* __restrict__ conv_w, const float* __restrict__ conv_b,
    const float* __restrict__ lin_w, const float* __restrict__ lin_b,
    ushort* __restrict__ x_out, float* __restrict__ xn_out,
    float* __restrict__ p_out, float* __restrict__ logp_out,
    const float* __restrict__ expW, ushort* __restrict__ expWb)
{
    if (blockIdx.x >= 1024) {            // W conversion blocks
        const int k = blockIdx.x - 1024;
        const float* src = expW + k * 4096 + threadIdx.x * 16;
        ushort* dst = expWb + k * 4096 + threadIdx.x * 16;
        #pragma unroll
        for (int i = 0; i < 4; ++i) {
            float4 v = *reinterpret_cast<const float4*>(src + i * 4);
            ushort4 o;
            o.x = f2bf(v.x); o.y = f2bf(v.y); o.z = f2bf(v.z); o.w = f2bf(v.w);
            *reinterpret_cast<ushort4*>(dst + i * 4) = o;
        }
        return;
    }

    const int tok = blockIdx.x * 4 + (threadIdx.x >> 6);   // 0..4095
    const int t   = tok & 511;
    const int c   = threadIdx.x & 63;

    const int id0 = tokens[tok];
    float h0 = emb[id0 * 64 + c];
    float hm = 0.0f, hp = 0.0f;
    if (t > 0)   hm = emb[tokens[tok - 1] * 64 + c];
    if (t < 511) hp = emb[tokens[tok + 1] * 64 + c];

    float hc = conv_w[c * 3 + 0] * hm + conv_w[c * 3 + 1] * h0 +
               conv_w[c * 3 + 2] * hp + conv_b[c];

    // router matvec: lane j keeps logit j
    float myLg = 0.0f;
    #pragma unroll
    for (int j = 0; j < 17; ++j) {
        float v = redw(hc * lin_w[c * 17 + j]);
        if (c == j) myLg = v + lin_b[j];
    }
    // log_softmax over lanes 0..16 (register)
    float mx = (c < 17) ? myLg : -1e30f;
    #pragma unroll
    for (int m = 32; m >= 1; m >>= 1) mx = fmaxf(mx, __shfl_xor(mx, m));
    float ev = (c < 17) ? __expf(myLg - mx) : 0.0f;
    float se = redw(ev);
    float lse = __logf(se);
    if (c < 17) {
        float lp = myLg - mx - lse;
        logp_out[tok * 17 + c] = lp;
        p_out[tok * 17 + c]    = __expf(lp);
    }

    // project(h0)
    float n0 = sqrtf(fmaxf(redw(h0 * h0), EPS2));
    float xp = h0 * fminf(1.0f, MAXN / n0);
    // logmap0
    float n1 = sqrtf(fmaxf(redw(xp * xp), EPS2));
    float v1 = artanh_(n1) / n1 * xp;
    // expmap0
    float n2 = sqrtf(fmaxf(redw(v1 * v1), EPS2));
    float xv = tanh_pos(n2) / n2 * v1;

    x_out[tok * 64 + c] = f2bf(xv);
    float n3 = sqrtf(fmaxf(redw(xv * xv), EPS2));
    if (c == 0) xn_out[tok] = n3;
}

// ---------------------------------------------------------------------------
// K2: ONE WAVE per (16-token chunk, expert k) — 1088 blocks x 4 indep waves.
// Wave's 8 MFMAs (4 e-chunks x K=64) leave mv[c][q] in registers in chain
// layout: lane (lg,li) holds tokens lg*4+q, e = c*16+li. No LDS, no barrier;
// reductions over e = sum_c + red16; GLU pairing (e vs e+32) is in-thread
// (c vs c+2); each thread runs 4 independent token-chains (4x ILP).
// ---------------------------------------------------------------------------
__global__ __launch_bounds__(256) void k2_expert(
    const ushort* __restrict__ xb, const float* __restrict__ xn_in,
    const float* __restrict__ p_in, const ushort* __restrict__ Wb,
    const float* __restrict__ expB, const float* __restrict__ g_in,
    const float* __restrict__ b_in, __hip_bfloat16* __restrict__ yk_out)
{
    const int gid = blockIdx.x * 4 + (threadIdx.x >> 6);   // 0..4351
    const int l  = threadIdx.x & 63;
    const int k  = gid >> 8;            // 0..16
    const int chunk = gid & 255;        // 0..255
    const int tok0 = chunk * 16;
    const int lg = l >> 4, li = l & 15;
    const int d0 = lg * 8;

    // A-frags: x rows = 16 tokens of chunk
    const ushort* ap = xb + (tok0 + li) * 64 + d0;
    bf16x8 a0 = *reinterpret_cast<const bf16x8*>(ap);
    bf16x8 a1 = *reinterpret_cast<const bf16x8*>(ap + 32);

    // 4 e-chunks x 2 K-halves: mv[c][q] = mv[token lg*4+q][e=c*16+li]
    f32x4 mv[4];
    #pragma unroll
    for (int c = 0; c < 4; ++c) {
        const ushort* bp = Wb + k * 4096 + (c * 16 + li) * 64 + d0;
        bf16x8 b0 = *reinterpret_cast<const bf16x8*>(bp);
        bf16x8 b1 = *reinterpret_cast<const bf16x8*>(bp + 32);
        f32x4 acc = {0.f, 0.f, 0.f, 0.f};
        acc = __builtin_amdgcn_mfma_f32_16x16x32_bf16(a0, b0, acc, 0, 0, 0);
        acc = __builtin_amdgcn_mfma_f32_16x16x32_bf16(a1, b1, acc, 0, 0, 0);
        mv[c] = acc;
    }

    // projected bias (register-only): pb[c] = proj(expB[k])[c*16+li]
    float wv = expB[k * 64 + l];
    float sB = redw(wv * wv);
    float nB = sqrtf(fmaxf(sB, EPS2));
    float scB = fminf(1.0f, MAXN / nB);
    float y2 = sB * scB * scB;
    float pb[4];
    #pragma unroll
    for (int c = 0; c < 4; ++c) pb[c] = __shfl(wv, c * 16 + li) * scB;

    // LN params for e = li and 16+li
    float gq0 = g_in[k * 32 + li],      gq1 = g_in[k * 32 + 16 + li];
    float bq0 = b_in[k * 32 + li],      bq1 = b_in[k * 32 + 16 + li];

    #pragma unroll
    for (int q = 0; q < 4; ++q) {
        const int tok = tok0 + lg * 4 + q;
        float m0 = mv[0][q], m1 = mv[1][q], m2 = mv[2][q], m3 = mv[3][q];
        float xnv = xn_in[tok];
        float axnv = artanh_(xnv);

        // mobius matvec scaling
        float mn = sqrtf(fmaxf(red16(m0*m0 + m1*m1 + m2*m2 + m3*m3), EPS2));
        float tv = tanh_pos(mn / xnv * axnv);
        float cf = tv / mn;
        float xa0 = cf * m0, xa1 = cf * m1, xa2 = cf * m2, xa3 = cf * m3;
        float x2 = tv * tv;

        // mobius_add(xa, pb)
        float xy = red16(xa0*pb[0] + xa1*pb[1] + xa2*pb[2] + xa3*pb[3]);
        float ca = 1.0f + 2.0f * xy + y2;
        float cb = 1.0f - x2;
        float rden = 1.0f / fmaxf(1.0f + 2.0f * xy + x2 * y2, EPS);
        float y0 = (ca * xa0 + cb * pb[0]) * rden;
        float y1 = (ca * xa1 + cb * pb[1]) * rden;
        float y2c = (ca * xa2 + cb * pb[2]) * rden;
        float y3 = (ca * xa3 + cb * pb[3]) * rden;

        // project
        float s2 = red16(y0*y0 + y1*y1 + y2c*y2c + y3*y3);
        float nP = sqrtf(fmaxf(s2, EPS2));
        float scP = fminf(1.0f, MAXN / nP);
        y0 *= scP; y1 *= scP; y2c *= scP; y3 *= scP;

        // logmap0
        float n2 = sqrtf(fmaxf(s2 * scP * scP, EPS2));
        float lc = artanh_(n2) / n2;
        float yt0 = lc * y0, yt1 = lc * y1, yt2 = lc * y2c, yt3 = lc * y3;

        // GLU: a = e 0..31 (c=0,1), g = e 32..63 (c=2,3) — in-thread
        float gl0 = yt0 * sigmoid_(yt2);
        float gl1 = yt1 * sigmoid_(yt3);

        // LayerNorm over 32
        float mu = red16(gl0 + gl1) * (1.0f / 32.0f);
        float sq = red16(gl0*gl0 + gl1*gl1) * (1.0f / 32.0f);
        float rstd = rsqrtf(fmaxf(sq - mu * mu, 0.0f) + 1e-5f);
        float ln0 = (gl0 - mu) * rstd * gq0 + bq0;
        float ln1 = (gl1 - mu) * rstd * gq1 + bq1;

        // expmap0
        float n3 = sqrtf(fmaxf(red16(ln0*ln0 + ln1*ln1), EPS2));
        float tc = tanh_pos(n3) / n3;

        // p-weighted partial
        float wq = p_in[tok * 17 + k] * tc;
        ushort* dst = reinterpret_cast<ushort*>(yk_out) + (size_t)tok * 544 + k * 32;
        dst[li]      = f2bf(wq * ln0);
        dst[16 + li] = f2bf(wq * ln1);
    }
}

// ---------------------------------------------------------------------------
// K3: ya_bf16[tok][e] = sum_k yk[tok][k][e]
// ---------------------------------------------------------------------------
__global__ __launch_bounds__(256) void k3_reduce(
    const __hip_bfloat16* __restrict__ yk, ushort* __restrict__ yab)
{
    int idx = blockIdx.x * 256 + threadIdx.x;    // 0..131071
    int tok = idx >> 5, e = idx & 31;
    const __hip_bfloat16* p = yk + (size_t)tok * 17 * 32 + e;
    float s = 0.0f;
    #pragma unroll
    for (int k = 0; k < 17; ++k) s += __bfloat162float(p[k * 32]);
    yab[idx] = f2bf(s);
}

// ---------------------------------------------------------------------------
// K4: M_r = T_r S_r^T (in-block); Z[b,r,t,:] = ya[t,:] . M_r via MFMA.
// block = (b, r, t-quarter) = 1280 blocks, 4 waves.
// r==0 blocks also zero the pmax buffer for k5's atomicMax.
// ---------------------------------------------------------------------------
__global__ __launch_bounds__(256) void k4_rel(
    const ushort* __restrict__ yab, const float* __restrict__ relT,
    const float* __restrict__ relS, ushort* __restrict__ Z,
    unsigned long long* __restrict__ pmax)
{
    const int blk = blockIdx.x;
    const int b = blk / 160;
    const int rem = blk % 160;
    const int r = rem >> 2, tq = rem & 3;
    __shared__ float Ts[32][33], Ss[32][33], Mm[32][33];
    __shared__ float Zb[128][33];
    const int tid = threadIdx.x;
    const int l = tid & 63, w = tid >> 6;

    if (r == 0 && tid < 128)
        pmax[(size_t)b * 512 + tq * 128 + tid] = 0ull;

    // stage T_r, S_r
    {
        int d = tid >> 3, e0 = (tid & 7) * 4;
        float4 wT = *reinterpret_cast<const float4*>(&relT[r * 1024 + tid * 4]);
        float4 wS = *reinterpret_cast<const float4*>(&relS[r * 1024 + tid * 4]);
        Ts[d][e0 + 0] = wT.x; Ts[d][e0 + 1] = wT.y;
        Ts[d][e0 + 2] = wT.z; Ts[d][e0 + 3] = wT.w;
        Ss[d][e0 + 0] = wS.x; Ss[d][e0 + 1] = wS.y;
        Ss[d][e0 + 2] = wS.z; Ss[d][e0 + 3] = wS.w;
    }
    __syncthreads();

    // M[d][dp] = sum_e Ts[d][e] * Ss[dp][e]
    {
        int d = tid >> 3, dp0 = (tid & 7) * 4;
        float m0 = 0.f, m1 = 0.f, m2 = 0.f, m3 = 0.f;
        #pragma unroll
        for (int e = 0; e < 32; ++e) {
            float tvv = Ts[d][e];
            m0 = fmaf(tvv, Ss[dp0 + 0][e], m0);
            m1 = fmaf(tvv, Ss[dp0 + 1][e], m1);
            m2 = fmaf(tvv, Ss[dp0 + 2][e], m2);
            m3 = fmaf(tvv, Ss[dp0 + 3][e], m3);
        }
        Mm[d][dp0 + 0] = m0; Mm[d][dp0 + 1] = m1;
        Mm[d][dp0 + 2] = m2; Mm[d][dp0 + 3] = m3;
    }
    __syncthreads();

    // B-frags: B[k=d][col=dp] = M[d][dp]
    bf16x8 bm0, bm1;
    #pragma unroll
    for (int i = 0; i < 8; ++i) {
        int d = (l >> 4) * 8 + i;
        bm0[i] = (short)f2bf(Mm[d][(l & 15)]);
        bm1[i] = (short)f2bf(Mm[d][16 + (l & 15)]);
    }

    // A-frags from yab; wave w covers t-tiles w*2, w*2+1 of this 128-t quarter
    #pragma unroll
    for (int s = 0; s < 2; ++s) {
        int trow = tq * 128 + (w * 2 + s) * 16 + (l & 15);
        bf16x8 a = *reinterpret_cast<const bf16x8*>(
            yab + ((size_t)(b * 512) + trow) * 32 + (l >> 4) * 8);
        f32x4 acc0 = {0.f, 0.f, 0.f, 0.f}, acc1 = {0.f, 0.f, 0.f, 0.f};
        acc0 = __builtin_amdgcn_mfma_f32_16x16x32_bf16(a, bm0, acc0, 0, 0, 0);
        acc1 = __builtin_amdgcn_mfma_f32_16x16x32_bf16(a, bm1, acc1, 0, 0, 0);
        #pragma unroll
        for (int q = 0; q < 4; ++q) {
            int lr = (w * 2 + s) * 16 + (l >> 4) * 4 + q;
            Zb[lr][(l & 15)]      = acc0[q];
            Zb[lr][16 + (l & 15)] = acc1[q];
        }
    }
    __syncthreads();

    // coalesced bf16 write
    {
        int t2 = tid >> 1, half = tid & 1;
        union { ushort u[16]; uint4 q[2]; } pk;
        #pragma unroll
        for (int j = 0; j < 16; ++j) pk.u[j] = f2bf(Zb[t2][half * 16 + j]);
        size_t off = ((size_t)(b * 40 + r) * 512 + tq * 128 + t2) * 32 + half * 16;
        *reinterpret_cast<uint4*>(Z + off)     = pk.q[0];
        *reinterpret_cast<uint4*>(Z + off + 8) = pk.q[1];
    }
}

// ---------------------------------------------------------------------------
// K5: score = max_r Z_r . ya^T via MFMA; b-frags (yab) loaded once; fused
// column-argmax partials into pmax via packed uint64 atomicMax.
// (round-8 structure — full occupancy, no exit fence)
// ---------------------------------------------------------------------------
__global__ __launch_bounds__(1024) void k5_scores(
    const ushort* __restrict__ Z, const ushort* __restrict__ yab,
    float* __restrict__ score_out, unsigned long long* __restrict__ pmax)
{
    __shared__ float L[4][64][64];               // 64 KB
    __shared__ unsigned long long pk_s[16][64];  // 8 KB

    const int blk = blockIdx.x;
    const int b = blk >> 6, tile = blk & 63;
    const int it = (tile >> 3) * 64, jt = (tile & 7) * 64;
    const int w = threadIdx.x >> 6, lane = threadIdx.x & 63;
    const int q = w >> 2, s = w & 3;        // r-chunk, i-subtile
    const int i0 = it + s * 16;
    const int arow = i0 + (lane & 15);
    const int koff = (lane >> 4) * 8;

    // b-fragments: yab rows for the 4 j-subtiles (r-invariant)
    bf16x8 bb[4];
    #pragma unroll
    for (int c = 0; c < 4; ++c) {
        int jrow = jt + c * 16 + (lane & 15);
        bb[c] = *reinterpret_cast<const bf16x8*>(
            yab + ((size_t)(b * 512) + jrow) * 32 + koff);
    }

    f32x4 runmax[4];
    #pragma unroll
    for (int c = 0; c < 4; ++c)
        #pragma unroll
        for (int qq = 0; qq < 4; ++qq) runmax[c][qq] = -3.0e38f;

    const int r0 = q * 10;
    #pragma unroll 2
    for (int r = r0; r < r0 + 10; ++r) {
        bf16x8 a = *reinterpret_cast<const bf16x8*>(
            Z + ((size_t)(b * 40 + r) * 512 + arow) * 32 + koff);
        #pragma unroll
        for (int c = 0; c < 4; ++c) {
            f32x4 acc = {0.f, 0.f, 0.f, 0.f};
            acc = __builtin_amdgcn_mfma_f32_16x16x32_bf16(a, bb[c], acc, 0, 0, 0);
            #pragma unroll
            for (int qq = 0; qq < 4; ++qq) runmax[c][qq] = fmaxf(runmax[c][qq], acc[qq]);
        }
    }

    // deposit partial max into LDS quadrant q
    #pragma unroll
    for (int c = 0; c < 4; ++c) {
        #pragma unroll
        for (int qq = 0; qq < 4; ++qq) {
            int li = s * 16 + (lane >> 4) * 4 + qq;
            int lj = c * 16 + (lane & 15);
            L[q][li][lj] = runmax[c][qq];
        }
    }
    __syncthreads();

    // combine 4 r-chunks, scale, diag-mask, store; track column argmax
    {
        const int jl = threadIdx.x & 63, ig = threadIdx.x >> 6;
        const int gj = jt + jl;
        float bestv = -3.0e38f; int besti = it;
        #pragma unroll
        for (int p = 0; p < 4; ++p) {
            int i = ig + p * 16;
            float v = fmaxf(fmaxf(L[0][i][jl], L[1][i][jl]),
                            fmaxf(L[2][i][jl], L[3][i][jl])) * (1.0f / 32.0f);
            int gi = it + i;
            if (gi == gj) v = -1e9f;
            score_out[((size_t)b * 512 + gi) * 512 + gj] = v;
            if (v > bestv) { bestv = v; besti = gi; }
        }
        unsigned int ub = __float_as_uint(bestv);
        unsigned int ok = (ub >> 31) ? ~ub : (ub | 0x80000000u);
        pk_s[ig][jl] = ((unsigned long long)ok << 32) | (unsigned int)(511 - besti);
    }
    __syncthreads();
    if (threadIdx.x < 64) {
        unsigned long long best = pk_s[0][threadIdx.x];
        #pragma unroll
        for (int g = 1; g < 16; ++g) {
            unsigned long long v = pk_s[g][threadIdx.x];
            if (v > best) best = v;
        }
        atomicMax(&pmax[(size_t)b * 512 + jt + threadIdx.x], best);
    }
}

// ---------------------------------------------------------------------------
// K6: tree[b,j] = 511 - (pmax & 0x1ff)
// ---------------------------------------------------------------------------
__global__ __launch_bounds__(256) void k6_tree(
    const unsigned long long* __restrict__ pmax, float* __restrict__ tree)
{
    int idx = blockIdx.x * 256 + threadIdx.x;    // 0..4095
    tree[idx] = (float)(511 - (int)(pmax[idx] & 0x1ffull));
}

// ---------------------------------------------------------------------------
extern "C" void kernel_launch(void* const* d_in, const int* in_sizes, int n_in,
                              void* d_out, int out_size, void* d_ws, size_t ws_size,
                              hipStream_t stream)
{
    const int*   tokens  = (const int*)  d_in[0];
    const float* emb     = (const float*)d_in[1];
    const float* conv_w  = (const float*)d_in[2];
    const float* conv_b  = (const float*)d_in[3];
    const float* lin_w   = (const float*)d_in[4];
    const float* lin_b   = (const float*)d_in[5];
    const float* expW    = (const float*)d_in[6];
    const float* expB    = (const float*)d_in[7];
    const float* ln_g    = (const float*)d_in[8];
    const float* ln_b    = (const float*)d_in[9];
    const float* relT    = (const float*)d_in[10];
    const float* relS    = (const float*)d_in[11];

    float* out = (float*)d_out;
    float* tree_out  = out;                    // [8*512]
    float* score_out = out + 4096;             // [8*512*512]
    float* logp_out  = out + 4096 + 2097152;   // [8*512*17]

    float* ws = (float*)d_ws;
    ushort* xb_ws  = (ushort*)ws;               // 262144 bf16 (131072 f32 slots)
    float*  xn_ws  = ws + 131072;               // 4096
    float*  p_ws   = ws + 135168;               // 69632
    ushort* Wb_ws  = (ushort*)(ws + 204800);    // 69632 bf16 (34816 slots)
    ushort* yab_ws = (ushort*)(ws + 239616);    // 131072 bf16 (65536 slots)
    __hip_bfloat16* yk_ws = (__hip_bfloat16*)(ws + 305152);   // 2228224 bf16
    ushort* Z_ws   = (ushort*)(ws + 1419264);   // 5242880 bf16 (2621440 slots)
    unsigned long long* pmax_ws =
        (unsigned long long*)(ws + 4040704);    // 4096 u64

    k1_token<<<1041, 256, 0, stream>>>(tokens, emb, conv_w, conv_b, lin_w, lin_b,
                                       xb_ws, xn_ws, p_ws, logp_out, expW, Wb_ws);
    k2_expert<<<1088, 256, 0, stream>>>(xb_ws, xn_ws, p_ws, Wb_ws, expB, ln_g, ln_b, yk_ws);
    k3_reduce<<<512, 256, 0, stream>>>(yk_ws, yab_ws);
    k4_rel<<<1280, 256, 0, stream>>>(yab_ws, relT, relS, Z_ws, pmax_ws);
    k5_scores<<<512, 1024, 0, stream>>>(Z_ws, yab_ws, score_out, pmax_ws);
    k6_tree<<<16, 256, 0, stream>>>(pmax_ws, tree_out);
}

// Round 16
// 60.569 us; speedup vs baseline: 1.1332x; 1.0323x over previous
//
#include <hip/hip_runtime.h>
#include <hip/hip_bf16.h>
#include <math.h>

#define EPS   1e-5f
#define EPS2  (1e-5f * 1e-5f)
#define MAXN  (1.0f - 1e-4f)

typedef __attribute__((ext_vector_type(8))) short bf16x8;
typedef __attribute__((ext_vector_type(4))) float f32x4;

__device__ __forceinline__ float artanh_(float x) {   // fast: 0.5*log((1+x)/(1-x))
    x = fminf(fmaxf(x, -1.0f + 1e-5f), 1.0f - 1e-5f);
    return 0.5f * __logf((1.0f + x) / (1.0f - x));
}
__device__ __forceinline__ float tanh_pos(float x) {  // x >= 0
    float t = __expf(-2.0f * x);
    return (1.0f - t) / (1.0f + t);
}
__device__ __forceinline__ float redw(float v) {   // sum over 64 lanes
    #pragma unroll
    for (int m = 32; m >= 1; m >>= 1) v += __shfl_xor(v, m);
    return v;
}
__device__ __forceinline__ float red16(float v) {  // sum over 16-lane group
    v += __shfl_xor(v, 1); v += __shfl_xor(v, 2);
    v += __shfl_xor(v, 4); v += __shfl_xor(v, 8);
    return v;
}
__device__ __forceinline__ float red8(float v) {   // sum over 8-lane group
    v += __shfl_xor(v, 1); v += __shfl_xor(v, 2); v += __shfl_xor(v, 4);
    return v;
}
__device__ __forceinline__ float sigmoid_(float z) { return 1.0f / (1.0f + __expf(-z)); }
__device__ __forceinline__ ushort f2bf(float f) {
    union { __hip_bfloat16 b; ushort u; } cv;
    cv.b = __float2bfloat16(f);
    return cv.u;
}

// ---------------------------------------------------------------------------
// K1: blocks 0..1023: per-token embed gather, conv3, router log_softmax,
//     tangent roundtrip; x written as bf16 (sole consumer is k2's MFMA).
//     blocks 1024..1040: convert expW[k] -> bf16.
// ---------------------------------------------------------------------------
__global__ __launch_bounds__(256) void k1_token(
    const int* __restrict__ tokens, const float* __restrict__ emb,
    const float* __restrict__ conv_w, const float* __restrict__ conv_b,
    const float* __restrict__ lin_w, const float* __restrict__ lin_b,
    ushort* __restrict__ x_out, float* __restrict__ xn_out,
    float* __restrict__ p_out, float* __restrict__ logp_out,
    const float* __restrict__ expW, ushort* __restrict__ expWb)
{
    if (blockIdx.x >= 1024) {            // W conversion blocks
        const int k = blockIdx.x - 1024;
        const float* src = expW + k * 4096 + threadIdx.x * 16;
        ushort* dst = expWb + k * 4096 + threadIdx.x * 16;
        #pragma unroll
        for (int i = 0; i < 4; ++i) {
            float4 v = *reinterpret_cast<const float4*>(src + i * 4);
            ushort4 o;
            o.x = f2bf(v.x); o.y = f2bf(v.y); o.z = f2bf(v.z); o.w = f2bf(v.w);
            *reinterpret_cast<ushort4*>(dst + i * 4) = o;
        }
        return;
    }

    const int tok = blockIdx.x * 4 + (threadIdx.x >> 6);   // 0..4095
    const int t   = tok & 511;
    const int c   = threadIdx.x & 63;

    const int id0 = tokens[tok];
    float h0 = emb[id0 * 64 + c];
    float hm = 0.0f, hp = 0.0f;
    if (t > 0)   hm = emb[tokens[tok - 1] * 64 + c];
    if (t < 511) hp = emb[tokens[tok + 1] * 64 + c];

    float hc = conv_w[c * 3 + 0] * hm + conv_w[c * 3 + 1] * h0 +
               conv_w[c * 3 + 2] * hp + conv_b[c];

    // router matvec: lane j keeps logit j
    float myLg = 0.0f;
    #pragma unroll
    for (int j = 0; j < 17; ++j) {
        float v = redw(hc * lin_w[c * 17 + j]);
        if (c == j) myLg = v + lin_b[j];
    }
    // log_softmax over lanes 0..16 (register)
    float mx = (c < 17) ? myLg : -1e30f;
    #pragma unroll
    for (int m = 32; m >= 1; m >>= 1) mx = fmaxf(mx, __shfl_xor(mx, m));
    float ev = (c < 17) ? __expf(myLg - mx) : 0.0f;
    float se = redw(ev);
    float lse = __logf(se);
    if (c < 17) {
        float lp = myLg - mx - lse;
        logp_out[tok * 17 + c] = lp;
        p_out[tok * 17 + c]    = __expf(lp);
    }

    // project(h0)
    float n0 = sqrtf(fmaxf(redw(h0 * h0), EPS2));
    float xp = h0 * fminf(1.0f, MAXN / n0);
    // logmap0
    float n1 = sqrtf(fmaxf(redw(xp * xp), EPS2));
    float v1 = artanh_(n1) / n1 * xp;
    // expmap0
    float n2 = sqrtf(fmaxf(redw(v1 * v1), EPS2));
    float xv = tanh_pos(n2) / n2 * v1;

    x_out[tok * 64 + c] = f2bf(xv);
    float n3 = sqrtf(fmaxf(redw(xv * xv), EPS2));
    if (c == 0) xn_out[tok] = n3;
}

// ---------------------------------------------------------------------------
// K2: one (16-token chunk, expert k) per block — 4352 blocks.
// MFMA matvec from pre-converted bf16 (pure 16B loads, no cvt); projected
// bias computed per-wave in registers (no LDS, no wave-0 serialization);
// all small params loaded per-thread directly. Only mv_s bounce + 1 barrier.
// ---------------------------------------------------------------------------
__global__ __launch_bounds__(256) void k2_expert(
    const ushort* __restrict__ xb, const float* __restrict__ xn_in,
    const float* __restrict__ p_in, const ushort* __restrict__ Wb,
    const float* __restrict__ expB, const float* __restrict__ g_in,
    const float* __restrict__ b_in, __hip_bfloat16* __restrict__ yk_out)
{
    __shared__ float mv_s[16][65];   // mv transpose bounce (2-way banks = free)

    const int tid = threadIdx.x;
    const int l = tid & 63, w = tid >> 6;
    const int tg = tid >> 4, eg = tid & 15;
    const int k = blockIdx.x >> 8;          // 0..16
    const int chunk = blockIdx.x & 255;     // 0..255
    const int tok0 = chunk * 16;

    // ---- MFMA matvec: mv[tok][e] = sum_d x[tok][d] * W[k][e][d]
    {
        const int d0 = (l >> 4) * 8;
        const ushort* ap = xb + (tok0 + (l & 15)) * 64 + d0;
        const ushort* bp = Wb + k * 4096 + (16 * w + (l & 15)) * 64 + d0;
        bf16x8 a0 = *reinterpret_cast<const bf16x8*>(ap);
        bf16x8 a1 = *reinterpret_cast<const bf16x8*>(ap + 32);
        bf16x8 b0 = *reinterpret_cast<const bf16x8*>(bp);
        bf16x8 b1 = *reinterpret_cast<const bf16x8*>(bp + 32);
        f32x4 acc = {0.f, 0.f, 0.f, 0.f};
        acc = __builtin_amdgcn_mfma_f32_16x16x32_bf16(a0, b0, acc, 0, 0, 0);
        acc = __builtin_amdgcn_mfma_f32_16x16x32_bf16(a1, b1, acc, 0, 0, 0);
        #pragma unroll
        for (int q = 0; q < 4; ++q)
            mv_s[(l >> 4) * 4 + q][16 * w + (l & 15)] = acc[q];
    }

    // ---- projected bias: per-wave, register-only (no LDS, no barrier dep)
    float wv = expB[k * 64 + l];
    float s  = redw(wv * wv);
    float nB = sqrtf(fmaxf(s, EPS2));
    float scB = fminf(1.0f, MAXN / nB);
    float y2 = s * scB * scB;
    float pb0 = __shfl(wv, eg * 4 + 0) * scB;
    float pb1 = __shfl(wv, eg * 4 + 1) * scB;
    float pb2 = __shfl(wv, eg * 4 + 2) * scB;
    float pb3 = __shfl(wv, eg * 4 + 3) * scB;

    // ---- small params: direct per-thread loads (L2/L1 broadcast)
    const int c0 = 4 * (eg & 7);
    float4 gq = *reinterpret_cast<const float4*>(g_in + k * 32 + c0);
    float4 bq = *reinterpret_cast<const float4*>(b_in + k * 32 + c0);
    float pk  = p_in[(tok0 + tg) * 17 + k];
    float xnv = xn_in[tok0 + tg];
    float axnv = artanh_(xnv);

    __syncthreads();

    float4 mvq = *reinterpret_cast<const float4*>(&mv_s[tg][eg * 4]);
    float mv0 = mvq.x, mv1 = mvq.y, mv2 = mvq.z, mv3 = mvq.w;

    // mobius matvec scaling
    float mn = sqrtf(fmaxf(red16(mv0*mv0 + mv1*mv1 + mv2*mv2 + mv3*mv3), EPS2));
    float tv = tanh_pos(mn / xnv * axnv);
    float cf = tv / mn;
    float xa0 = cf * mv0, xa1 = cf * mv1, xa2 = cf * mv2, xa3 = cf * mv3;
    float x2 = tv * tv;

    // mobius_add(xa, pb)
    float xy = red16(xa0*pb0 + xa1*pb1 + xa2*pb2 + xa3*pb3);
    float ca = 1.0f + 2.0f * xy + y2;
    float cb = 1.0f - x2;
    float den = fmaxf(1.0f + 2.0f * xy + x2 * y2, EPS);
    float rden = 1.0f / den;
    float y0 = (ca * xa0 + cb * pb0) * rden;
    float y1 = (ca * xa1 + cb * pb1) * rden;
    float y2c = (ca * xa2 + cb * pb2) * rden;
    float y3 = (ca * xa3 + cb * pb3) * rden;

    // project
    float s2 = red16(y0*y0 + y1*y1 + y2c*y2c + y3*y3);
    float nP = sqrtf(fmaxf(s2, EPS2));
    float scP = fminf(1.0f, MAXN / nP);
    y0 *= scP; y1 *= scP; y2c *= scP; y3 *= scP;

    // logmap0
    float n2 = sqrtf(fmaxf(s2 * scP * scP, EPS2));
    float lc = artanh_(n2) / n2;
    float yt0 = lc * y0, yt1 = lc * y1, yt2 = lc * y2c, yt3 = lc * y3;

    // GLU via lane-pair exchange (eg<8 hold a, eg>=8 hold g); halves duplicate
    float pr0 = __shfl_xor(yt0, 8), pr1 = __shfl_xor(yt1, 8);
    float pr2 = __shfl_xor(yt2, 8), pr3 = __shfl_xor(yt3, 8);
    float gl0, gl1, gl2, gl3;
    if (eg < 8) {
        gl0 = yt0 * sigmoid_(pr0); gl1 = yt1 * sigmoid_(pr1);
        gl2 = yt2 * sigmoid_(pr2); gl3 = yt3 * sigmoid_(pr3);
    } else {
        gl0 = pr0 * sigmoid_(yt0); gl1 = pr1 * sigmoid_(yt1);
        gl2 = pr2 * sigmoid_(yt2); gl3 = pr3 * sigmoid_(yt3);
    }

    // LayerNorm over 32 (each 8-lane half holds full set)
    float mu = red8(gl0 + gl1 + gl2 + gl3) * (1.0f / 32.0f);
    float sq = red8(gl0*gl0 + gl1*gl1 + gl2*gl2 + gl3*gl3) * (1.0f / 32.0f);
    float rstd = rsqrtf(fmaxf(sq - mu * mu, 0.0f) + 1e-5f);
    float ln0 = (gl0 - mu) * rstd * gq.x + bq.x;
    float ln1 = (gl1 - mu) * rstd * gq.y + bq.y;
    float ln2 = (gl2 - mu) * rstd * gq.z + bq.z;
    float ln3 = (gl3 - mu) * rstd * gq.w + bq.w;

    // expmap0
    float n3 = sqrtf(fmaxf(red8(ln0*ln0 + ln1*ln1 + ln2*ln2 + ln3*ln3), EPS2));
    float tc = tanh_pos(n3) / n3;

    // p-weighted partial for this expert
    float wq = pk * tc;

    if (eg < 8) {
        int tok = tok0 + tg;
        ushort4 o;
        o.x = f2bf(wq * ln0);
        o.y = f2bf(wq * ln1);
        o.z = f2bf(wq * ln2);
        o.w = f2bf(wq * ln3);
        *reinterpret_cast<ushort4*>(
            reinterpret_cast<ushort*>(yk_out) + ((size_t)tok * 17 + k) * 32 + c0) = o;
    }
}

// ---------------------------------------------------------------------------
// K3: ya_bf16[tok][e] = sum_k yk[tok][k][e]
// ---------------------------------------------------------------------------
__global__ __launch_bounds__(256) void k3_reduce(
    const __hip_bfloat16* __restrict__ yk, ushort* __restrict__ yab)
{
    int idx = blockIdx.x * 256 + threadIdx.x;    // 0..131071
    int tok = idx >> 5, e = idx & 31;
    const __hip_bfloat16* p = yk + (size_t)tok * 17 * 32 + e;
    float s = 0.0f;
    #pragma unroll
    for (int k = 0; k < 17; ++k) s += __bfloat162float(p[k * 32]);
    yab[idx] = f2bf(s);
}

// ---------------------------------------------------------------------------
// K4: M_r = T_r S_r^T (in-block); Z[b,r,t,:] = ya[t,:] . M_r via MFMA.
// block = (b, r, t-quarter) = 1280 blocks, 4 waves.
// r==0 blocks also zero the pmax buffer for k5's atomicMax.
// ---------------------------------------------------------------------------
__global__ __launch_bounds__(256) void k4_rel(
    const ushort* __restrict__ yab, const float* __restrict__ relT,
    const float* __restrict__ relS, ushort* __restrict__ Z,
    unsigned long long* __restrict__ pmax)
{
    const int blk = blockIdx.x;
    const int b = blk / 160;
    const int rem = blk % 160;
    const int r = rem >> 2, tq = rem & 3;
    __shared__ float Ts[32][33], Ss[32][33], Mm[32][33];
    __shared__ float Zb[128][33];
    const int tid = threadIdx.x;
    const int l = tid & 63, w = tid >> 6;

    if (r == 0 && tid < 128)
        pmax[(size_t)b * 512 + tq * 128 + tid] = 0ull;

    // stage T_r, S_r
    {
        int d = tid >> 3, e0 = (tid & 7) * 4;
        float4 wT = *reinterpret_cast<const float4*>(&relT[r * 1024 + tid * 4]);
        float4 wS = *reinterpret_cast<const float4*>(&relS[r * 1024 + tid * 4]);
        Ts[d][e0 + 0] = wT.x; Ts[d][e0 + 1] = wT.y;
        Ts[d][e0 + 2] = wT.z; Ts[d][e0 + 3] = wT.w;
        Ss[d][e0 + 0] = wS.x; Ss[d][e0 + 1] = wS.y;
        Ss[d][e0 + 2] = wS.z; Ss[d][e0 + 3] = wS.w;
    }
    __syncthreads();

    // M[d][dp] = sum_e Ts[d][e] * Ss[dp][e]
    {
        int d = tid >> 3, dp0 = (tid & 7) * 4;
        float m0 = 0.f, m1 = 0.f, m2 = 0.f, m3 = 0.f;
        #pragma unroll
        for (int e = 0; e < 32; ++e) {
            float tvv = Ts[d][e];
            m0 = fmaf(tvv, Ss[dp0 + 0][e], m0);
            m1 = fmaf(tvv, Ss[dp0 + 1][e], m1);
            m2 = fmaf(tvv, Ss[dp0 + 2][e], m2);
            m3 = fmaf(tvv, Ss[dp0 + 3][e], m3);
        }
        Mm[d][dp0 + 0] = m0; Mm[d][dp0 + 1] = m1;
        Mm[d][dp0 + 2] = m2; Mm[d][dp0 + 3] = m3;
    }
    __syncthreads();

    // B-frags: B[k=d][col=dp] = M[d][dp]
    bf16x8 bm0, bm1;
    #pragma unroll
    for (int i = 0; i < 8; ++i) {
        int d = (l >> 4) * 8 + i;
        bm0[i] = (short)f2bf(Mm[d][(l & 15)]);
        bm1[i] = (short)f2bf(Mm[d][16 + (l & 15)]);
    }

    // A-frags from yab; wave w covers t-tiles w*2, w*2+1 of this 128-t quarter
    #pragma unroll
    for (int s = 0; s < 2; ++s) {
        int trow = tq * 128 + (w * 2 + s) * 16 + (l & 15);
        bf16x8 a = *reinterpret_cast<const bf16x8*>(
            yab + ((size_t)(b * 512) + trow) * 32 + (l >> 4) * 8);
        f32x4 acc0 = {0.f, 0.f, 0.f, 0.f}, acc1 = {0.f, 0.f, 0.f, 0.f};
        acc0 = __builtin_amdgcn_mfma_f32_16x16x32_bf16(a, bm0, acc0, 0, 0, 0);
        acc1 = __builtin_amdgcn_mfma_f32_16x16x32_bf16(a, bm1, acc1, 0, 0, 0);
        #pragma unroll
        for (int q = 0; q < 4; ++q) {
            int lr = (w * 2 + s) * 16 + (l >> 4) * 4 + q;
            Zb[lr][(l & 15)]      = acc0[q];
            Zb[lr][16 + (l & 15)] = acc1[q];
        }
    }
    __syncthreads();

    // coalesced bf16 write
    {
        int t2 = tid >> 1, half = tid & 1;
        union { ushort u[16]; uint4 q[2]; } pk;
        #pragma unroll
        for (int j = 0; j < 16; ++j) pk.u[j] = f2bf(Zb[t2][half * 16 + j]);
        size_t off = ((size_t)(b * 40 + r) * 512 + tq * 128 + t2) * 32 + half * 16;
        *reinterpret_cast<uint4*>(Z + off)     = pk.q[0];
        *reinterpret_cast<uint4*>(Z + off + 8) = pk.q[1];
    }
}

// ---------------------------------------------------------------------------
// K5: score = max_r Z_r . ya^T via MFMA; b-frags (yab) loaded once; fused
// column-argmax partials into pmax via packed uint64 atomicMax.
// (round-8 structure — full occupancy, no exit fence)
// ---------------------------------------------------------------------------
__global__ __launch_bounds__(1024) void k5_scores(
    const ushort* __restrict__ Z, const ushort* __restrict__ yab,
    float* __restrict__ score_out, unsigned long long* __restrict__ pmax)
{
    __shared__ float L[4][64][64];               // 64 KB
    __shared__ unsigned long long pk_s[16][64];  // 8 KB

    const int blk = blockIdx.x;
    const int b = blk >> 6, tile = blk & 63;
    const int it = (tile >> 3) * 64, jt = (tile & 7) * 64;
    const int w = threadIdx.x >> 6, lane = threadIdx.x & 63;
    const int q = w >> 2, s = w & 3;        // r-chunk, i-subtile
    const int i0 = it + s * 16;
    const int arow = i0 + (lane & 15);
    const int koff = (lane >> 4) * 8;

    // b-fragments: yab rows for the 4 j-subtiles (r-invariant)
    bf16x8 bb[4];
    #pragma unroll
    for (int c = 0; c < 4; ++c) {
        int jrow = jt + c * 16 + (lane & 15);
        bb[c] = *reinterpret_cast<const bf16x8*>(
            yab + ((size_t)(b * 512) + jrow) * 32 + koff);
    }

    f32x4 runmax[4];
    #pragma unroll
    for (int c = 0; c < 4; ++c)
        #pragma unroll
        for (int qq = 0; qq < 4; ++qq) runmax[c][qq] = -3.0e38f;

    const int r0 = q * 10;
    #pragma unroll 2
    for (int r = r0; r < r0 + 10; ++r) {
        bf16x8 a = *reinterpret_cast<const bf16x8*>(
            Z + ((size_t)(b * 40 + r) * 512 + arow) * 32 + koff);
        #pragma unroll
        for (int c = 0; c < 4; ++c) {
            f32x4 acc = {0.f, 0.f, 0.f, 0.f};
            acc = __builtin_amdgcn_mfma_f32_16x16x32_bf16(a, bb[c], acc, 0, 0, 0);
            #pragma unroll
            for (int qq = 0; qq < 4; ++qq) runmax[c][qq] = fmaxf(runmax[c][qq], acc[qq]);
        }
    }

    // deposit partial max into LDS quadrant q
    #pragma unroll
    for (int c = 0; c < 4; ++c) {
        #pragma unroll
        for (int qq = 0; qq < 4; ++qq) {
            int li = s * 16 + (lane >> 4) * 4 + qq;
            int lj = c * 16 + (lane & 15);
            L[q][li][lj] = runmax[c][qq];
        }
    }
    __syncthreads();

    // combine 4 r-chunks, scale, diag-mask, store; track column argmax
    {
        const int jl = threadIdx.x & 63, ig = threadIdx.x >> 6;
        const int gj = jt + jl;
        float bestv = -3.0e38f; int besti = it;
        #pragma unroll
        for (int p = 0; p < 4; ++p) {
            int i = ig + p * 16;
            float v = fmaxf(fmaxf(L[0][i][jl], L[1][i][jl]),
                            fmaxf(L[2][i][jl], L[3][i][jl])) * (1.0f / 32.0f);
            int gi = it + i;
            if (gi == gj) v = -1e9f;
            score_out[((size_t)b * 512 + gi) * 512 + gj] = v;
            if (v > bestv) { bestv = v; besti = gi; }
        }
        unsigned int ub = __float_as_uint(bestv);
        unsigned int ok = (ub >> 31) ? ~ub : (ub | 0x80000000u);
        pk_s[ig][jl] = ((unsigned long long)ok << 32) | (unsigned int)(511 - besti);
    }
    __syncthreads();
    if (threadIdx.x < 64) {
        unsigned long long best = pk_s[0][threadIdx.x];
        #pragma unroll
        for (int g = 1; g < 16; ++g) {
            unsigned long long v = pk_s[g][threadIdx.x];
            if (v > best) best = v;
        }
        atomicMax(&pmax[(size_t)b * 512 + jt + threadIdx.x], best);
    }
}

// ---------------------------------------------------------------------------
// K6: tree[b,j] = 511 - (pmax & 0x1ff)
// ---------------------------------------------------------------------------
__global__ __launch_bounds__(256) void k6_tree(
    const unsigned long long* __restrict__ pmax, float* __restrict__ tree)
{
    int idx = blockIdx.x * 256 + threadIdx.x;    // 0..4095
    tree[idx] = (float)(511 - (int)(pmax[idx] & 0x1ffull));
}

// ---------------------------------------------------------------------------
extern "C" void kernel_launch(void* const* d_in, const int* in_sizes, int n_in,
                              void* d_out, int out_size, void* d_ws, size_t ws_size,
                              hipStream_t stream)
{
    const int*   tokens  = (const int*)  d_in[0];
    const float* emb     = (const float*)d_in[1];
    const float* conv_w  = (const float*)d_in[2];
    const float* conv_b  = (const float*)d_in[3];
    const float* lin_w   = (const float*)d_in[4];
    const float* lin_b   = (const float*)d_in[5];
    const float* expW    = (const float*)d_in[6];
    const float* expB    = (const float*)d_in[7];
    const float* ln_g    = (const float*)d_in[8];
    const float* ln_b    = (const float*)d_in[9];
    const float* relT    = (const float*)d_in[10];
    const float* relS    = (const float*)d_in[11];

    float* out = (float*)d_out;
    float* tree_out  = out;                    // [8*512]
    float* score_out = out + 4096;             // [8*512*512]
    float* logp_out  = out + 4096 + 2097152;   // [8*512*17]

    float* ws = (float*)d_ws;
    ushort* xb_ws  = (ushort*)ws;               // 262144 bf16 (131072 f32 slots)
    float*  xn_ws  = ws + 131072;               // 4096
    float*  p_ws   = ws + 135168;               // 69632
    ushort* Wb_ws  = (ushort*)(ws + 204800);    // 69632 bf16 (34816 slots)
    ushort* yab_ws = (ushort*)(ws + 239616);    // 131072 bf16 (65536 slots)
    __hip_bfloat16* yk_ws = (__hip_bfloat16*)(ws + 305152);   // 2228224 bf16
    ushort* Z_ws   = (ushort*)(ws + 1419264);   // 5242880 bf16 (2621440 slots)
    unsigned long long* pmax_ws =
        (unsigned long long*)(ws + 4040704);    // 4096 u64

    k1_token<<<1041, 256, 0, stream>>>(tokens, emb, conv_w, conv_b, lin_w, lin_b,
                                       xb_ws, xn_ws, p_ws, logp_out, expW, Wb_ws);
    k2_expert<<<4352, 256, 0, stream>>>(xb_ws, xn_ws, p_ws, Wb_ws, expB, ln_g, ln_b, yk_ws);
    k3_reduce<<<512, 256, 0, stream>>>(yk_ws, yab_ws);
    k4_rel<<<1280, 256, 0, stream>>>(yab_ws, relT, relS, Z_ws, pmax_ws);
    k5_scores<<<512, 1024, 0, stream>>>(Z_ws, yab_ws, score_out, pmax_ws);
    k6_tree<<<16, 256, 0, stream>>>(pmax_ws, tree_out);
}